// Round 7
// baseline (216.735 us; speedup 1.0000x reference)
//
#include <hip/hip_runtime.h>
#include <math.h>

// Problem constants (fixed): B=4, C=256, H=64, W=128, D=4, 81 shifts, C/R=16
// out: [B, 81, H, W] fp32 (2,654,208 elements)
// ws (floats): [0) pooled 82,944  [82944) At 82,944  [165888) cpart 2,654,208

#define HH 64
#define WW 128
#define CC 256
#define BB 4

typedef float v2f __attribute__((ext_vector_type(2)));

// ---------------------------------------------------------------------------
// Kernel A: pooled[b, s, c] = sum_{h,w} f1[b,c,h,w] * f2pad[b,c,h+i,w+j]
// One 576-thread block (9 waves) per (b,c) plane; thread (h=t/9, di=t%9)
// owns a full row. UNCHANGED.
// ---------------------------------------------------------------------------
__global__ __launch_bounds__(576) void corr_pool_kernel(
    const float* __restrict__ f1, const float* __restrict__ f2,
    float* __restrict__ pooled) {
  const int t  = threadIdx.x;
  const int bc = blockIdx.x;                    // b*256 + c
  const float* f1p = f1 + (size_t)bc * (HH * WW);
  const float* f2p = f2 + (size_t)bc * (HH * WW);

  __shared__ float4 f2s4[72 * 35];              // 40,320 B; reused for reduce

  // --- stage f2 plane with zero halo (single barrier) ---
  const float4 z4 = make_float4(0.f, 0.f, 0.f, 0.f);
  for (int u = t; u < 72 * 35; u += 576) {
    const int rl = u / 35, k = u - rl * 35;     // padded row, padded chunk
    const int gr = rl - 4;                      // f2 row
    float4 v = z4;
    if ((unsigned)gr < 64u && k >= 1 && k <= 32)
      v = *(const float4*)(f2p + (gr << 7) + ((k - 1) << 2));
    f2s4[u] = v;
  }
  __syncthreads();

  // --- stage 1: thread (h, di) accumulates s9[j] over its full row ---
  const int h  = t / 9;                         // 0..63
  const int di = t - h * 9;                     // 0..8
  const float4* f2row = &f2s4[(h + di) * 35];   // padded row h+di
  const float* f1row  = f1p + (h << 7);

  float s9[9];
#pragma unroll
  for (int j = 0; j < 9; ++j) s9[j] = 0.f;

  alignas(16) float f1c[16], f2wc[24];
#pragma unroll
  for (int m = 0; m < 4; ++m)
    *(float4*)&f1c[4 * m] = *(const float4*)(f1row + (m << 2));
#pragma unroll
  for (int m = 0; m < 6; ++m) *(float4*)&f2wc[4 * m] = f2row[m];

  for (int seg = 0; seg < 8; ++seg) {
    const int nxt = (seg < 7) ? seg + 1 : 7;    // clamped (dup load on last)
    alignas(16) float f1n[16], f2wn[24];
#pragma unroll
    for (int m = 0; m < 4; ++m)
      *(float4*)&f1n[4 * m] =
          *(const float4*)(f1row + (nxt << 4) + (m << 2));
#pragma unroll
    for (int m = 0; m < 6; ++m) *(float4*)&f2wn[4 * m] = f2row[(nxt << 2) + m];

#pragma unroll
    for (int k = 0; k < 16; ++k) {
      const float a = f1c[k];
#pragma unroll
      for (int j = 0; j < 9; ++j) s9[j] += a * f2wc[k + j];
    }
#pragma unroll
    for (int m = 0; m < 16; ++m) f1c[m] = f1n[m];
#pragma unroll
    for (int m = 0; m < 24; ++m) f2wc[m] = f2wn[m];
  }

  // --- stage 2: parallel column reduction (all 576 threads) ---
  __syncthreads();                              // stage-1 LDS reads done
  float* red  = (float*)f2s4;                   // [64][81]
  float* red2 = red + 64 * 81;                  // [7][81]
#pragma unroll
  for (int j = 0; j < 9; ++j) red[h * 81 + di * 9 + j] = s9[j];
  __syncthreads();

  if (t < 567) {                                // 7 groups x 81 cols
    const int col = t % 81, g = t / 81;
    const int r0 = g * 9, r1 = (g == 6) ? 64 : r0 + 9;
    float acc = 0.f;
#pragma unroll 3
    for (int rr = r0; rr < r1; ++rr) acc += red[rr * 81 + col];
    red2[g * 81 + col] = acc;
  }
  __syncthreads();

  if (t < 81) {
    float acc = 0.f;
#pragma unroll
    for (int g = 0; g < 7; ++g) acc += red2[g * 81 + t];
    const int b = bc >> 8, c = bc & 255;
    pooled[(size_t)(b * 81 + t) * 256 + c] = acc;   // raw sum (/8192 in B)
  }
}

// ---------------------------------------------------------------------------
// Kernel B: At[b, c, s] = sigmoid(MLP(pooled/8192)). Transposed output for
// kernel C's wave-uniform coefficient s_loads. UNCHANGED.
// ---------------------------------------------------------------------------
__global__ __launch_bounds__(256) void mlp_kernel(
    const float* __restrict__ pooled, const float* __restrict__ w1,
    const float* __restrict__ b1, const float* __restrict__ w2,
    const float* __restrict__ b2, float* __restrict__ At) {
  const int bs = blockIdx.x;                    // b*81 + s
  const int t  = threadIdx.x;
  const int b  = bs / 81;
  const int s  = bs - b * 81;
  __shared__ float p[256];
  __shared__ float hid[16];

  p[t] = pooled[(size_t)bs * 256 + t] * (1.0f / 8192.0f);
  __syncthreads();

  const int g = t >> 4, ln = t & 15;
  float acc = 0.f;
#pragma unroll
  for (int m = 0; m < 16; ++m) {
    const int c = (m << 4) + ln;
    acc += w1[(g << 8) + c] * p[c];
  }
  acc += __shfl_xor(acc, 1);
  acc += __shfl_xor(acc, 2);
  acc += __shfl_xor(acc, 4);
  acc += __shfl_xor(acc, 8);
  if (ln == 0) hid[g] = acc + b1[g];
  __syncthreads();

  float acc2 = b2[t];
#pragma unroll
  for (int k = 0; k < 16; ++k) acc2 += w2[(t << 4) + k] * hid[k];
  const float sv = 1.0f / (1.0f + __expf(-acc2));
  At[((size_t)(b * 256 + t)) * 81 + s] = sv;    // transposed: [b][c][81]
}

// ---------------------------------------------------------------------------
// Async 16B global->LDS copy: lane l's 16B lands at ldsbase + l*16.
// ---------------------------------------------------------------------------
__device__ __forceinline__ void async16(const float* g, void* lds) {
  __builtin_amdgcn_global_load_lds(
      (const __attribute__((address_space(1))) void*)g,
      (__attribute__((address_space(3))) void*)lds, 16, 0, 0);
}

// ---------------------------------------------------------------------------
// Kernel C: channel-half partial of
//   out[b, i*9+j, h, w] = (1/256) sum_c At[b,c,i*9+j]*f1[c,h,w]*f2[c,h+i-4,w+j-4]
// Round-16: RAW BARRIERS + PACKED FP32. Diagnosis from r0-r6 invariance
// (dur 63-68, VALUBusy 37-41% across ALL structures; FETCH 82->33MB with
// NO dur change): VALU work is fixed ~24us; the rest is per-iteration
// serial latency {coef s_load ~300cy -> window reads ~200cy -> FMA ~340cy}
// that 2.25 waves/SIMD can't cover, PLUS r6's __syncthreads vmcnt(0) drain
// killing the prefetch every iteration. Fixes:
//  (a) m201 discipline: raw s_barrier + counted vmcnt(2). Every wave
//      issues EXACTLY 2 asyncs/iter (dummies -> LDS trash slot, clamped
//      addrs) so the count is wave-uniform. Mid-barrier = k-data visible;
//      end-barrier = buf[cur] safe from k+2 overwrite. Prefetch now has a
//      full iteration of flight and is never drained.
//  (b) float2 ext-vector FMA block -> v_pk_fma_f32/v_pk_mul_f32 (VOP3P),
//      halving FMA instruction count.
// Success: dur <= 50us. Fail (flat ~63+): limiter is outside the pipe
// model (SQ issue/clocks) -> pivot to corr_pool.
// ---------------------------------------------------------------------------
__global__ __launch_bounds__(576) void out_kernel(
    const float* __restrict__ f1, const float* __restrict__ f2,
    const float* __restrict__ At, float* __restrict__ out,
    float* __restrict__ part) {
  // bijective XCD swizzle: 256 blocks, XCD k gets work k*32..k*32+31
  const int bid  = blockIdx.x;
  const int work = (bid & 7) * 32 + (bid >> 3);
  const int rt   = work & 31;                   // row-pair tile
  const int half = (work >> 5) & 1;             // channel half
  const int b    = work >> 6;
  const int h0   = rt << 1;

  const int t    = threadIdx.x;
  const int wv   = t >> 6;                      // wave = i shift, 0..8
  const int lane = t & 63;
  const int r    = lane >> 5;                   // 0..1 (row within pair)
  const int cidx = lane & 31;                   // float4 column
  const int w0   = cidx << 2;
  const int h    = h0 + r;
  const int iu   = __builtin_amdgcn_readfirstlane(wv);  // SGPR i

  // [buf][ch-of-pair][row: 0..9 f2 halo, 10..11 f1][col] -- 24,576 B
  __shared__ float4 st[2][2][12][32];
  __shared__ float4 trash[64];                  // dummy async target, 1 KB

  const int c0 = half << 7;
  const float* f1pl = f1 + ((size_t)b * 256 + c0) * 8192;
  const float* f2pl = f2 + ((size_t)b * 256 + c0) * 8192;
  const float* Aa   = At + ((size_t)(b * 256 + c0)) * 81 + iu * 9;

  // --- stage unit assignment: 12 units = 2ch x (5 f2 row-pairs + 1 f1) ---
  const int chA   = (wv >= 6) ? 1 : 0;
  const int slotA = wv - 6 * chA;               // 0..5
  const bool isF1A = (slotA == 5);
  const int prowA  = h0 - 4 + 2 * slotA;        // pair start row
  const bool validA = isF1A || ((unsigned)prowA < 63u);  // both rows valid
  const int crowA  = isF1A ? h0 : ((prowA < 0) ? 0 : ((prowA > 62) ? 62 : prowA));
  const float* gA = (isF1A ? f1pl : f2pl) + crowA * 128 +
                    (size_t)chA * 8192 + lane * 4;
  float4* dA0 = validA ? &st[0][chA][2 * slotA][0] : &trash[0];
  float4* dA1 = validA ? &st[1][chA][2 * slotA][0] : &trash[0];

  const bool hasB  = (wv < 3);
  const int slotB  = (hasB ? wv : 0) + 3;       // 3..5
  const bool isF1B = (slotB == 5);
  const int prowB  = h0 - 4 + 2 * slotB;
  const bool validB = hasB && (isF1B || ((unsigned)prowB < 63u));
  const int crowB  = isF1B ? h0 : ((prowB < 0) ? 0 : ((prowB > 62) ? 62 : prowB));
  const float* gB = (isF1B ? f1pl : f2pl) + crowB * 128 +
                    (size_t)8192 + lane * 4;    // ch 1
  float4* dB0 = validB ? &st[0][1][2 * slotB][0] : &trash[0];
  float4* dB1 = validB ? &st[1][1][2 * slotB][0] : &trash[0];

  // --- pre-zero both buffers (covers never-staged invalid halo rows) ---
  {
    const float4 z4 = make_float4(0.f, 0.f, 0.f, 0.f);
    float4* stf = &st[0][0][0][0];
    for (int u = t; u < 2 * 2 * 12 * 32; u += 576) stf[u] = z4;
  }
  __syncthreads();

  // --- prologue: stage channel pair k=0 into buf 0 (2 asyncs per wave) ---
  async16(gA, dA0);
  async16(gB, dB0);

  v2f acc2[9][2];
#pragma unroll
  for (int j = 0; j < 9; ++j) {
    acc2[j][0] = (v2f)(0.f);
    acc2[j][1] = (v2f)(0.f);
  }

  const bool vA = (cidx > 0);
  const bool vC = (cidx < 31);
  const int cxm1 = vA ? cidx - 1 : cidx;
  const int cxp1 = vC ? cidx + 1 : cidx;
  const int riu  = r + iu;                      // LDS f2 row for this wave

  for (int k = 0; k < 64; ++k) {
    const int cur = k & 1;

    // --- 1. issue stage for k+1 into buf[cur^1] (2 asyncs per wave) ---
    const int adv = (k < 63) ? 16384 : 0;       // 2 channels fwd (dup @63)
    gA += adv; gB += adv;
    float4* dA = cur ? dA0 : dA1;               // nxt buffer
    float4* dB = cur ? dB0 : dB1;
    async16(gA, dA);
    async16(gB, dB);

    // --- 2. counted wait: own k-stage (oldest 2) done; k+1 in flight ---
    asm volatile("s_waitcnt vmcnt(2)" ::: "memory");
    __builtin_amdgcn_s_barrier();               // all waves' k-data in LDS

    // --- 3. consume channel pair (2k, 2k+1) from st[cur] ---
    const float* ca = Aa + (size_t)(2 * k) * 81;  // wave-uniform -> s_load
#pragma unroll
    for (int sub = 0; sub < 2; ++sub) {
      const float* cf = ca + sub * 81;
      const float4 x4 = st[cur][sub][10 + r][cidx];
      const float4 A4 = st[cur][sub][riu][cxm1];
      const float4 B4 = st[cur][sub][riu][cidx];
      const float4 C4 = st[cur][sub][riu][cxp1];

      alignas(16) float f2r[12];
      f2r[0]  = vA ? A4.x : 0.f;
      f2r[1]  = vA ? A4.y : 0.f;
      f2r[2]  = vA ? A4.z : 0.f;
      f2r[3]  = vA ? A4.w : 0.f;
      f2r[4]  = B4.x; f2r[5] = B4.y; f2r[6] = B4.z; f2r[7] = B4.w;
      f2r[8]  = vC ? C4.x : 0.f;
      f2r[9]  = vC ? C4.y : 0.f;
      f2r[10] = vC ? C4.z : 0.f;
      f2r[11] = vC ? C4.w : 0.f;

      const v2f xx01 = {x4.x, x4.y};
      const v2f xx23 = {x4.z, x4.w};

#pragma unroll
      for (int j = 0; j < 9; ++j) {
        const float wj = cf[j];
        const v2f w2  = {wj, wj};
        const v2f p01 = {f2r[j],     f2r[j + 1]};
        const v2f p23 = {f2r[j + 2], f2r[j + 3]};
        acc2[j][0] += w2 * (xx01 * p01);        // v_pk_mul + v_pk_fma
        acc2[j][1] += w2 * (xx23 * p23);
      }
    }

    // --- 4. end barrier: buf[cur] consumed before k+2 overwrites it ---
    __builtin_amdgcn_s_barrier();
  }

  // retire dangling dup-stage asyncs before LDS goes out of scope
  asm volatile("s_waitcnt vmcnt(0)" ::: "memory");

  // --- epilogue: wave i writes its 9 j-planes, 2 rows x 128 px ---
  float* dst = half ? part : out;
  const float inv = 1.0f / 256.0f;
#pragma unroll
  for (int j = 0; j < 9; ++j) {
    float4 o;
    o.x = acc2[j][0].x * inv;
    o.y = acc2[j][0].y * inv;
    o.z = acc2[j][1].x * inv;
    o.w = acc2[j][1].y * inv;
    *(float4*)(dst + (((size_t)(b * 81 + iu * 9 + j) * 64 + h) << 7) + w0) = o;
  }
}

// ---------------------------------------------------------------------------
// Combine: out += channel-half-1 partial. 663,552 float4s, grid 2592 x 256.
// ---------------------------------------------------------------------------
__global__ __launch_bounds__(256) void combine_kernel(
    float* __restrict__ out, const float* __restrict__ part) {
  const size_t idx = (size_t)blockIdx.x * 256 + threadIdx.x;  // float4 index
  float4* o4       = (float4*)out;
  const float4* p4 = (const float4*)part;
  const float4 a = o4[idx], p = p4[idx];
  float4 rv;
  rv.x = a.x + p.x; rv.y = a.y + p.y; rv.z = a.z + p.z; rv.w = a.w + p.w;
  o4[idx] = rv;
}

// ---------------------------------------------------------------------------
extern "C" void kernel_launch(void* const* d_in, const int* in_sizes, int n_in,
                              void* d_out, int out_size, void* d_ws, size_t ws_size,
                              hipStream_t stream) {
  const float* feat1 = (const float*)d_in[0];
  const float* feat2 = (const float*)d_in[1];
  const float* w1    = (const float*)d_in[2];
  const float* b1    = (const float*)d_in[3];
  const float* w2    = (const float*)d_in[4];
  const float* b2    = (const float*)d_in[5];
  float* out = (float*)d_out;

  float* pooled = (float*)d_ws;                 // 82,944 floats
  float* At     = pooled + 82944;               // 82,944 floats
  float* cpart  = At + 82944;                   // 2,654,208 floats

  corr_pool_kernel<<<1024, 576, 0, stream>>>(feat1, feat2, pooled);
  mlp_kernel<<<4 * 81, 256, 0, stream>>>(pooled, w1, b1, w2, b2, At);
  out_kernel<<<256, 576, 0, stream>>>(feat1, feat2, At, out, cpart);
  combine_kernel<<<2592, 256, 0, stream>>>(out, cpart);
}

// Round 8
// 206.072 us; speedup vs baseline: 1.0517x; 1.0517x over previous
//
#include <hip/hip_runtime.h>
#include <math.h>

// Problem constants (fixed): B=4, C=256, H=64, W=128, D=4, 81 shifts, C/R=16
// out: [B, 81, H, W] fp32 (2,654,208 elements)
// ws (floats): [0) pooled 82,944  [82944) At 82,944  [165888) cpart 2,654,208

#define HH 64
#define WW 128
#define CC 256
#define BB 4

typedef float v2f __attribute__((ext_vector_type(2)));

// ---------------------------------------------------------------------------
// Kernel A: pooled[b, s, c] = sum_{h,w} f1[b,c,h,w] * f2pad[b,c,h+i,w+j]
// One 576-thread block (9 waves) per (b,c) plane; thread (h=t/9, di=t%9)
// owns a full row. UNCHANGED.
// ---------------------------------------------------------------------------
__global__ __launch_bounds__(576) void corr_pool_kernel(
    const float* __restrict__ f1, const float* __restrict__ f2,
    float* __restrict__ pooled) {
  const int t  = threadIdx.x;
  const int bc = blockIdx.x;                    // b*256 + c
  const float* f1p = f1 + (size_t)bc * (HH * WW);
  const float* f2p = f2 + (size_t)bc * (HH * WW);

  __shared__ float4 f2s4[72 * 35];              // 40,320 B; reused for reduce

  // --- stage f2 plane with zero halo (single barrier) ---
  const float4 z4 = make_float4(0.f, 0.f, 0.f, 0.f);
  for (int u = t; u < 72 * 35; u += 576) {
    const int rl = u / 35, k = u - rl * 35;     // padded row, padded chunk
    const int gr = rl - 4;                      // f2 row
    float4 v = z4;
    if ((unsigned)gr < 64u && k >= 1 && k <= 32)
      v = *(const float4*)(f2p + (gr << 7) + ((k - 1) << 2));
    f2s4[u] = v;
  }
  __syncthreads();

  // --- stage 1: thread (h, di) accumulates s9[j] over its full row ---
  const int h  = t / 9;                         // 0..63
  const int di = t - h * 9;                     // 0..8
  const float4* f2row = &f2s4[(h + di) * 35];   // padded row h+di
  const float* f1row  = f1p + (h << 7);

  float s9[9];
#pragma unroll
  for (int j = 0; j < 9; ++j) s9[j] = 0.f;

  alignas(16) float f1c[16], f2wc[24];
#pragma unroll
  for (int m = 0; m < 4; ++m)
    *(float4*)&f1c[4 * m] = *(const float4*)(f1row + (m << 2));
#pragma unroll
  for (int m = 0; m < 6; ++m) *(float4*)&f2wc[4 * m] = f2row[m];

  for (int seg = 0; seg < 8; ++seg) {
    const int nxt = (seg < 7) ? seg + 1 : 7;    // clamped (dup load on last)
    alignas(16) float f1n[16], f2wn[24];
#pragma unroll
    for (int m = 0; m < 4; ++m)
      *(float4*)&f1n[4 * m] =
          *(const float4*)(f1row + (nxt << 4) + (m << 2));
#pragma unroll
    for (int m = 0; m < 6; ++m) *(float4*)&f2wn[4 * m] = f2row[(nxt << 2) + m];

#pragma unroll
    for (int k = 0; k < 16; ++k) {
      const float a = f1c[k];
#pragma unroll
      for (int j = 0; j < 9; ++j) s9[j] += a * f2wc[k + j];
    }
#pragma unroll
    for (int m = 0; m < 16; ++m) f1c[m] = f1n[m];
#pragma unroll
    for (int m = 0; m < 24; ++m) f2wc[m] = f2wn[m];
  }

  // --- stage 2: parallel column reduction (all 576 threads) ---
  __syncthreads();                              // stage-1 LDS reads done
  float* red  = (float*)f2s4;                   // [64][81]
  float* red2 = red + 64 * 81;                  // [7][81]
#pragma unroll
  for (int j = 0; j < 9; ++j) red[h * 81 + di * 9 + j] = s9[j];
  __syncthreads();

  if (t < 567) {                                // 7 groups x 81 cols
    const int col = t % 81, g = t / 81;
    const int r0 = g * 9, r1 = (g == 6) ? 64 : r0 + 9;
    float acc = 0.f;
#pragma unroll 3
    for (int rr = r0; rr < r1; ++rr) acc += red[rr * 81 + col];
    red2[g * 81 + col] = acc;
  }
  __syncthreads();

  if (t < 81) {
    float acc = 0.f;
#pragma unroll
    for (int g = 0; g < 7; ++g) acc += red2[g * 81 + t];
    const int b = bc >> 8, c = bc & 255;
    pooled[(size_t)(b * 81 + t) * 256 + c] = acc;   // raw sum (/8192 in B)
  }
}

// ---------------------------------------------------------------------------
// Kernel B: At[b, c, s] = sigmoid(MLP(pooled/8192)). Transposed output for
// kernel C's contiguous per-(b,half) coefficient slices. UNCHANGED.
// ---------------------------------------------------------------------------
__global__ __launch_bounds__(256) void mlp_kernel(
    const float* __restrict__ pooled, const float* __restrict__ w1,
    const float* __restrict__ b1, const float* __restrict__ w2,
    const float* __restrict__ b2, float* __restrict__ At) {
  const int bs = blockIdx.x;                    // b*81 + s
  const int t  = threadIdx.x;
  const int b  = bs / 81;
  const int s  = bs - b * 81;
  __shared__ float p[256];
  __shared__ float hid[16];

  p[t] = pooled[(size_t)bs * 256 + t] * (1.0f / 8192.0f);
  __syncthreads();

  const int g = t >> 4, ln = t & 15;
  float acc = 0.f;
#pragma unroll
  for (int m = 0; m < 16; ++m) {
    const int c = (m << 4) + ln;
    acc += w1[(g << 8) + c] * p[c];
  }
  acc += __shfl_xor(acc, 1);
  acc += __shfl_xor(acc, 2);
  acc += __shfl_xor(acc, 4);
  acc += __shfl_xor(acc, 8);
  if (ln == 0) hid[g] = acc + b1[g];
  __syncthreads();

  float acc2 = b2[t];
#pragma unroll
  for (int k = 0; k < 16; ++k) acc2 += w2[(t << 4) + k] * hid[k];
  const float sv = 1.0f / (1.0f + __expf(-acc2));
  At[((size_t)(b * 256 + t)) * 81 + s] = sv;    // transposed: [b][c][81]
}

// ---------------------------------------------------------------------------
// Kernel C: channel-half partial of
//   out[b, i*9+j, h, w] = (1/256) sum_c At[b,c,i*9+j]*f1[c,h,w]*f2[c,h+i-4,w+j-4]
// Round-17: KILL BOTH SERIAL CHAINS. r7 proved the compiler inserts its own
// vmcnt(0) before ds_reads after global_load_lds (counted waits are invisible
// to its model; r4's null is thereby invalidated too). r6 (33MB FETCH, 6TB/s
// L2) exonerated all bandwidths. The two per-iter serial chains present in
// ALL rounds: (1) drain of freshly-issued staging loads, (2) coefficient
// s_load ~300cy. Fixes:
//  - Coefficients: block-start copy of the contiguous [128][81] At slice
//    into LDS (41.5 KB, fully coalesced). In-loop: uniform ds_read.
//  - Window staging: T14 reg-split. Load pair k+1's rows into named float4s
//    at iter TOP (global->VGPR); ds_write at iter BOTTOM. The compiler's
//    mandatory vmcnt wait lands at the ds_write -- AFTER ~500cy of FMA
//    cover. Load+write in the SAME iteration: nothing to re-serialize.
//  - One __syncthreads per iter publishes buf[nxt] (drains only covered
//    loads). Shared 9-wave tile (3x fetch sharing) + packed v2f retained.
// Success: dur 25-35us, VALUBusy 55-75%. Fail (flat >=60): limiter outside
// pipe model -> pivot to corr_pool, revert C to r3 body.
// ---------------------------------------------------------------------------
__global__ __launch_bounds__(576) void out_kernel(
    const float* __restrict__ f1, const float* __restrict__ f2,
    const float* __restrict__ At, float* __restrict__ out,
    float* __restrict__ part) {
  // bijective XCD swizzle: 256 blocks, XCD k gets work k*32..k*32+31
  const int bid  = blockIdx.x;
  const int work = (bid & 7) * 32 + (bid >> 3);
  const int rt   = work & 31;                   // row-pair tile
  const int half = (work >> 5) & 1;             // channel half
  const int b    = work >> 6;
  const int h0   = rt << 1;

  const int t    = threadIdx.x;
  const int wv   = t >> 6;                      // wave = i shift, 0..8
  const int lane = t & 63;
  const int r    = lane >> 5;                   // 0..1 (row within pair)
  const int cidx = lane & 31;                   // float4 column
  const int w0   = cidx << 2;
  const int h    = h0 + r;
  const int iu   = __builtin_amdgcn_readfirstlane(wv);  // SGPR i

  // [buf][ch-of-pair][row: 0..9 f2 halo, 10..11 f1][col] -- 24,576 B
  __shared__ float4 st[2][2][12][32];
  __shared__ float coefL[128 * 81];             // 41,472 B (At slice)

  const int c0 = half << 7;
  const float* f1pl = f1 + ((size_t)b * 256 + c0) * 8192;
  const float* f2pl = f2 + ((size_t)b * 256 + c0) * 8192;
  const float* Atb  = At + ((size_t)(b * 256 + c0)) * 81;

  // --- stage unit assignment: 12 units = 2ch x (5 f2 row-pairs + 1 f1) ---
  const int chA   = (wv >= 6) ? 1 : 0;
  const int slotA = wv - 6 * chA;               // 0..5
  const bool isF1A = (slotA == 5);
  const int prowA  = h0 - 4 + 2 * slotA;        // pair start row (even)
  const bool validA = isF1A || ((unsigned)prowA < 63u);
  const int crowA  = isF1A ? h0 : ((prowA < 0) ? 0 : ((prowA > 62) ? 62 : prowA));
  const float* gA = (isF1A ? f1pl : f2pl) + crowA * 128 +
                    (size_t)chA * 8192 + lane * 4;
  const int rowA_lds = isF1A ? (10) : (2 * slotA);   // +lane>>5 handled by [lane]

  const bool hasB  = (wv < 3);
  const int slotB  = (hasB ? wv : 0) + 3;       // 3..5
  const bool isF1B = (slotB == 5);
  const int prowB  = h0 - 4 + 2 * slotB;
  const bool validB = hasB && (isF1B || ((unsigned)prowB < 63u));
  const int crowB  = isF1B ? h0 : ((prowB < 0) ? 0 : ((prowB > 62) ? 62 : prowB));
  const float* gB = (isF1B ? f1pl : f2pl) + crowB * 128 +
                    (size_t)8192 + lane * 4;    // ch 1 of pair
  const int rowB_lds = isF1B ? (10) : (2 * slotB);

  // --- pre-zero window buffers (covers never-staged invalid halo rows) ---
  {
    const float4 z4 = make_float4(0.f, 0.f, 0.f, 0.f);
    float4* stf = &st[0][0][0][0];
    for (int u = t; u < 2 * 2 * 12 * 32; u += 576) stf[u] = z4;
  }
  __syncthreads();                              // zeros visible before writes

  // --- stage coefficients: contiguous 10,368-float copy, coalesced ---
  for (int u = t; u < 128 * 81; u += 576) coefL[u] = Atb[u];

  // --- prologue: load+write channel pair 0 into buf 0 ---
  {
    const float4 vA0 = *(const float4*)(gA);
    const float4 vB0 = *(const float4*)(gB);
    if (validA) (&st[0][chA][rowA_lds][0])[lane] = vA0;
    if (validB) (&st[0][1][rowB_lds][0])[lane] = vB0;
  }
  __syncthreads();                              // coef + pair0 visible

  v2f acc2[9][2];
#pragma unroll
  for (int j = 0; j < 9; ++j) {
    acc2[j][0] = (v2f)(0.f);
    acc2[j][1] = (v2f)(0.f);
  }

  const bool vA = (cidx > 0);
  const bool vC = (cidx < 31);
  const int cxm1 = vA ? cidx - 1 : cidx;
  const int cxp1 = vC ? cidx + 1 : cidx;
  const int riu  = r + iu;                      // LDS f2 row for this wave

  for (int k = 0; k < 64; ++k) {
    const int cur = k & 1, nxt = cur ^ 1;

    // --- 1. issue next pair's loads into registers (T14 issue-early) ---
    const int adv = (k < 63) ? 16384 : 0;       // 2 channels fwd (dup @63)
    gA += adv; gB += adv;
    const float4 vAn = *(const float4*)(gA);
    const float4 vBn = *(const float4*)(gB);

    // --- 2. consume channel pair (2k, 2k+1) from st[cur] + coefL ---
#pragma unroll
    for (int sub = 0; sub < 2; ++sub) {
      const float* cf = coefL + (size_t)(2 * k + sub) * 81 + iu * 9;
      const float4 x4 = st[cur][sub][10 + r][cidx];
      const float4 A4 = st[cur][sub][riu][cxm1];
      const float4 B4 = st[cur][sub][riu][cidx];
      const float4 C4 = st[cur][sub][riu][cxp1];

      alignas(16) float f2r[12];
      f2r[0]  = vA ? A4.x : 0.f;
      f2r[1]  = vA ? A4.y : 0.f;
      f2r[2]  = vA ? A4.z : 0.f;
      f2r[3]  = vA ? A4.w : 0.f;
      f2r[4]  = B4.x; f2r[5] = B4.y; f2r[6] = B4.z; f2r[7] = B4.w;
      f2r[8]  = vC ? C4.x : 0.f;
      f2r[9]  = vC ? C4.y : 0.f;
      f2r[10] = vC ? C4.z : 0.f;
      f2r[11] = vC ? C4.w : 0.f;

      const v2f xx01 = {x4.x, x4.y};
      const v2f xx23 = {x4.z, x4.w};

#pragma unroll
      for (int j = 0; j < 9; ++j) {
        const float wj = cf[j];
        const v2f w2  = {wj, wj};
        const v2f p01 = {f2r[j],     f2r[j + 1]};
        const v2f p23 = {f2r[j + 2], f2r[j + 3]};
        acc2[j][0] += w2 * (xx01 * p01);        // v_pk_mul + v_pk_fma
        acc2[j][1] += w2 * (xx23 * p23);
      }
    }

    // --- 3. write-late: publish pair k+1 into buf[nxt] ---
    if (validA) (&st[nxt][chA][rowA_lds][0])[lane] = vAn;
    if (validB) (&st[nxt][1][rowB_lds][0])[lane] = vBn;

    // --- 4. one barrier per iter: buf[nxt] published, buf[cur] released ---
    __syncthreads();
  }

  // --- epilogue: wave i writes its 9 j-planes, 2 rows x 128 px ---
  float* dst = half ? part : out;
  const float inv = 1.0f / 256.0f;
#pragma unroll
  for (int j = 0; j < 9; ++j) {
    float4 o;
    o.x = acc2[j][0].x * inv;
    o.y = acc2[j][0].y * inv;
    o.z = acc2[j][1].x * inv;
    o.w = acc2[j][1].y * inv;
    *(float4*)(dst + (((size_t)(b * 81 + iu * 9 + j) * 64 + h) << 7) + w0) = o;
  }
}

// ---------------------------------------------------------------------------
// Combine: out += channel-half-1 partial. 663,552 float4s, grid 2592 x 256.
// ---------------------------------------------------------------------------
__global__ __launch_bounds__(256) void combine_kernel(
    float* __restrict__ out, const float* __restrict__ part) {
  const size_t idx = (size_t)blockIdx.x * 256 + threadIdx.x;  // float4 index
  float4* o4       = (float4*)out;
  const float4* p4 = (const float4*)part;
  const float4 a = o4[idx], p = p4[idx];
  float4 rv;
  rv.x = a.x + p.x; rv.y = a.y + p.y; rv.z = a.z + p.z; rv.w = a.w + p.w;
  o4[idx] = rv;
}

// ---------------------------------------------------------------------------
extern "C" void kernel_launch(void* const* d_in, const int* in_sizes, int n_in,
                              void* d_out, int out_size, void* d_ws, size_t ws_size,
                              hipStream_t stream) {
  const float* feat1 = (const float*)d_in[0];
  const float* feat2 = (const float*)d_in[1];
  const float* w1    = (const float*)d_in[2];
  const float* b1    = (const float*)d_in[3];
  const float* w2    = (const float*)d_in[4];
  const float* b2    = (const float*)d_in[5];
  float* out = (float*)d_out;

  float* pooled = (float*)d_ws;                 // 82,944 floats
  float* At     = pooled + 82944;               // 82,944 floats
  float* cpart  = At + 82944;                   // 2,654,208 floats

  corr_pool_kernel<<<1024, 576, 0, stream>>>(feat1, feat2, pooled);
  mlp_kernel<<<4 * 81, 256, 0, stream>>>(pooled, w1, b1, w2, b2, At);
  out_kernel<<<256, 576, 0, stream>>>(feat1, feat2, At, out, cpart);
  combine_kernel<<<2592, 256, 0, stream>>>(out, cpart);
}

// Round 9
// 199.618 us; speedup vs baseline: 1.0857x; 1.0323x over previous
//
#include <hip/hip_runtime.h>
#include <math.h>

// Problem constants (fixed): B=4, C=256, H=64, W=128, D=4, 81 shifts, C/R=16
// out: [B, 81, H, W] fp32 (2,654,208 elements)
// ws (floats): [0) pooled 82,944  [82944) At 82,944  [165888) cpart 2,654,208

#define HH 64
#define WW 128
#define CC 256
#define BB 4

// ---------------------------------------------------------------------------
// Kernel A: pooled[b, s, c] = sum_{h,w} f1[b,c,h,w] * f2pad[b,c,h+i,w+j]
// Round-18 v2: f1 STAGED IN LDS + NO REGISTER ROTATION. Old version re-read
// each f1 row from GLOBAL once per segment per thread (9 threads duplicate
// every row; per-seg dependent global round-trips = the out_kernel disease)
// and carried a 40-mov/seg register double-buffer the compiler collapses
// anyway (r2 lesson). Now: one coalesced staging pass puts f1 (32 KB) and
// haloed f2 (40 KB) in LDS; stage-1 is pure LDS->FMA, 10 ds_read_b128 +
// 144 FMA per seg, no in-loop global traffic, no rotation. LDS 73 KB ->
// 2 blocks/CU (18 waves); LDS latency ~120cy is coverable, unlike the
// ~900cy global chains. f1 9-lane same-address reads broadcast (free).
// ---------------------------------------------------------------------------
__global__ __launch_bounds__(576) void corr_pool_kernel(
    const float* __restrict__ f1, const float* __restrict__ f2,
    float* __restrict__ pooled) {
  const int t  = threadIdx.x;
  const int bc = blockIdx.x;                    // b*256 + c
  const float* f1p = f1 + (size_t)bc * (HH * WW);
  const float* f2p = f2 + (size_t)bc * (HH * WW);

  __shared__ float4 f2s4[72 * 35];              // 40,320 B; reused for reduce
  __shared__ float4 f1s4[64 * 32];              // 32,768 B f1 plane

  // --- stage f2 plane with zero halo + f1 plane (single barrier) ---
  const float4 z4 = make_float4(0.f, 0.f, 0.f, 0.f);
  for (int u = t; u < 72 * 35; u += 576) {
    const int rl = u / 35, k = u - rl * 35;     // padded row, padded chunk
    const int gr = rl - 4;                      // f2 row
    float4 v = z4;
    if ((unsigned)gr < 64u && k >= 1 && k <= 32)
      v = *(const float4*)(f2p + (gr << 7) + ((k - 1) << 2));
    f2s4[u] = v;
  }
  for (int u = t; u < 64 * 32; u += 576)
    f1s4[u] = *(const float4*)(f1p + (u << 2));
  __syncthreads();

  // --- stage 1: thread (h, di) accumulates s9[j] over its full row ---
  const int h  = t / 9;                         // 0..63
  const int di = t - h * 9;                     // 0..8
  const float4* f2row = &f2s4[(h + di) * 35];   // padded row h+di
  const float4* f1row = &f1s4[h * 32];

  float s9[9];
#pragma unroll
  for (int j = 0; j < 9; ++j) s9[j] = 0.f;

#pragma unroll
  for (int seg = 0; seg < 8; ++seg) {
    alignas(16) float f1c[16], f2wc[24];
#pragma unroll
    for (int m = 0; m < 4; ++m)
      *(float4*)&f1c[4 * m] = f1row[(seg << 2) + m];
#pragma unroll
    for (int m = 0; m < 6; ++m)
      *(float4*)&f2wc[4 * m] = f2row[(seg << 2) + m];

#pragma unroll
    for (int k = 0; k < 16; ++k) {
      const float a = f1c[k];
#pragma unroll
      for (int j = 0; j < 9; ++j) s9[j] += a * f2wc[k + j];
    }
  }

  // --- stage 2: parallel column reduction (all 576 threads) ---
  __syncthreads();                              // stage-1 LDS reads done
  float* red  = (float*)f2s4;                   // [64][81]
  float* red2 = red + 64 * 81;                  // [7][81]
#pragma unroll
  for (int j = 0; j < 9; ++j) red[h * 81 + di * 9 + j] = s9[j];
  __syncthreads();

  if (t < 567) {                                // 7 groups x 81 cols
    const int col = t % 81, g = t / 81;
    const int r0 = g * 9, r1 = (g == 6) ? 64 : r0 + 9;
    float acc = 0.f;
#pragma unroll 3
    for (int rr = r0; rr < r1; ++rr) acc += red[rr * 81 + col];
    red2[g * 81 + col] = acc;
  }
  __syncthreads();

  if (t < 81) {
    float acc = 0.f;
#pragma unroll
    for (int g = 0; g < 7; ++g) acc += red2[g * 81 + t];
    const int b = bc >> 8, c = bc & 255;
    pooled[(size_t)(b * 81 + t) * 256 + c] = acc;   // raw sum (/8192 in B)
  }
}

// ---------------------------------------------------------------------------
// Kernel B: At[b, c, s] = sigmoid(MLP(pooled/8192)). Transposed output for
// kernel C's wave-uniform coefficient s_loads. UNCHANGED.
// ---------------------------------------------------------------------------
__global__ __launch_bounds__(256) void mlp_kernel(
    const float* __restrict__ pooled, const float* __restrict__ w1,
    const float* __restrict__ b1, const float* __restrict__ w2,
    const float* __restrict__ b2, float* __restrict__ At) {
  const int bs = blockIdx.x;                    // b*81 + s
  const int t  = threadIdx.x;
  const int b  = bs / 81;
  const int s  = bs - b * 81;
  __shared__ float p[256];
  __shared__ float hid[16];

  p[t] = pooled[(size_t)bs * 256 + t] * (1.0f / 8192.0f);
  __syncthreads();

  const int g = t >> 4, ln = t & 15;
  float acc = 0.f;
#pragma unroll
  for (int m = 0; m < 16; ++m) {
    const int c = (m << 4) + ln;
    acc += w1[(g << 8) + c] * p[c];
  }
  acc += __shfl_xor(acc, 1);
  acc += __shfl_xor(acc, 2);
  acc += __shfl_xor(acc, 4);
  acc += __shfl_xor(acc, 8);
  if (ln == 0) hid[g] = acc + b1[g];
  __syncthreads();

  float acc2 = b2[t];
#pragma unroll
  for (int k = 0; k < 16; ++k) acc2 += w2[(t << 4) + k] * hid[k];
  const float sv = 1.0f / (1.0f + __expf(-acc2));
  At[((size_t)(b * 256 + t)) * 81 + s] = sv;    // transposed: [b][c][81]
}

// ---------------------------------------------------------------------------
// Kernel C: channel-half partial of
//   out[b, i*9+j, h, w] = (1/256) sum_c At[b,c,i*9+j]*f1[c,h,w]*f2[c,h+i-4,w+j-4]
// FROZEN at the round-3 shuffle-window body -- the measured optimum
// (63.1 us, VGPR 48). r2/r4/r7/r8 proved this compiler re-serializes every
// source-level pipeline variant (regs, async+counted vmcnt, reg-split);
// r1/r6 exonerated occupancy and bandwidth. Do not touch without a
// mechanism the compiler cannot defeat.
// ---------------------------------------------------------------------------
__global__ __launch_bounds__(64, 4) void out_kernel(
    const float* __restrict__ f1, const float* __restrict__ f2,
    const float* __restrict__ At, float* __restrict__ out,
    float* __restrict__ part) {
  // bid = x + 8*(i + 9*tq); tile = tq*8 + x keeps i-siblings on one XCD
  const int bid  = blockIdx.x;
  const int x    = bid & 7;
  const int q    = bid >> 3;                    // 0..287
  const int i    = q % 9;
  const int tq   = q / 9;                       // 0..31
  const int tile = tq * 8 + x;                  // 0..255
  const int half = tile & 1;
  const int rt   = (tile >> 1) & 31;
  const int b    = tile >> 6;
  const int h0   = rt << 1;

  const int t    = threadIdx.x;
  const int r    = t >> 5;                      // 0..1
  const int cidx = t & 31;
  const int w0   = cidx << 2;
  const int h    = h0 + r;
  const int hr   = h + i - 4;
  const bool rowok = ((unsigned)hr < 64u);

  float acc[9][4];
#pragma unroll
  for (int j = 0; j < 9; ++j)
#pragma unroll
    for (int k = 0; k < 4; ++k) acc[j][k] = 0.f;

  if (rowok) {
    const int c0 = half << 7;                   // 128-channel half base
    const float* pa1 = f1 + (size_t)b * (CC * 8192) + (size_t)c0 * 8192 +
                       (h << 7) + w0;
    const float* pa2 = f2 + (size_t)b * (CC * 8192) + (size_t)c0 * 8192 +
                       (hr << 7);
    const float* pb1 = pa1 + (size_t)64 * 8192; // paired channel c+64
    const float* pb2 = pa2 + (size_t)64 * 8192;
    const float* Aa  = At + (size_t)b * (CC * 81) + (size_t)c0 * 81 + i * 9;

    const bool vA  = (cidx > 0);
    const bool vC  = (cidx < 31);

    for (int c = 0; c < 64; ++c) {
      // --- 4 vector loads (two channels, center only) ---
      const float4 xa = *(const float4*)(pa1);
      const float4 aB = *(const float4*)(pa2 + w0);
      const float4 xb = *(const float4*)(pb1);
      const float4 bB = *(const float4*)(pb2 + w0);

      const float* ca = Aa + (size_t)c * 81;    // wave-uniform -> s_load
      const float* cb = ca + (size_t)64 * 81;

      const int adv = (c < 63) ? 8192 : 0;      // cndmask, no branch
      pa1 += adv; pa2 += adv; pb1 += adv; pb2 += adv;

      // --- neighbor window float4s from adjacent lanes (DS pipe, not TA) ---
      const float aAx = __shfl_up(aB.x, 1);
      const float aAy = __shfl_up(aB.y, 1);
      const float aAz = __shfl_up(aB.z, 1);
      const float aAw = __shfl_up(aB.w, 1);
      const float aCx = __shfl_down(aB.x, 1);
      const float aCy = __shfl_down(aB.y, 1);
      const float aCz = __shfl_down(aB.z, 1);
      const float aCw = __shfl_down(aB.w, 1);
      const float bAx = __shfl_up(bB.x, 1);
      const float bAy = __shfl_up(bB.y, 1);
      const float bAz = __shfl_up(bB.z, 1);
      const float bAw = __shfl_up(bB.w, 1);
      const float bCx = __shfl_down(bB.x, 1);
      const float bCy = __shfl_down(bB.y, 1);
      const float bCz = __shfl_down(bB.z, 1);
      const float bCw = __shfl_down(bB.w, 1);

      // --- channel a ---
      alignas(16) float f2ra[12];
      f2ra[0] = vA ? aAx : 0.f;
      f2ra[1] = vA ? aAy : 0.f;
      f2ra[2] = vA ? aAz : 0.f;
      f2ra[3] = vA ? aAw : 0.f;
      f2ra[4] = aB.x; f2ra[5] = aB.y; f2ra[6] = aB.z; f2ra[7] = aB.w;
      f2ra[8]  = vC ? aCx : 0.f;
      f2ra[9]  = vC ? aCy : 0.f;
      f2ra[10] = vC ? aCz : 0.f;
      f2ra[11] = vC ? aCw : 0.f;
      alignas(16) const float xxa[4] = {xa.x, xa.y, xa.z, xa.w};

#pragma unroll
      for (int j = 0; j < 9; ++j) {
        const float wj = ca[j];
#pragma unroll
        for (int k = 0; k < 4; ++k) acc[j][k] += wj * (xxa[k] * f2ra[k + j]);
      }

      // --- channel b (c+64) ---
      alignas(16) float f2rb[12];
      f2rb[0] = vA ? bAx : 0.f;
      f2rb[1] = vA ? bAy : 0.f;
      f2rb[2] = vA ? bAz : 0.f;
      f2rb[3] = vA ? bAw : 0.f;
      f2rb[4] = bB.x; f2rb[5] = bB.y; f2rb[6] = bB.z; f2rb[7] = bB.w;
      f2rb[8]  = vC ? bCx : 0.f;
      f2rb[9]  = vC ? bCy : 0.f;
      f2rb[10] = vC ? bCz : 0.f;
      f2rb[11] = vC ? bCw : 0.f;
      alignas(16) const float xxb[4] = {xb.x, xb.y, xb.z, xb.w};

#pragma unroll
      for (int j = 0; j < 9; ++j) {
        const float wj = cb[j];
#pragma unroll
        for (int k = 0; k < 4; ++k) acc[j][k] += wj * (xxb[k] * f2rb[k + j]);
      }
    }
  }

  float* dst = half ? part : out;
  const float inv = 1.0f / 256.0f;
#pragma unroll
  for (int j = 0; j < 9; ++j) {
    float4 o;
    o.x = acc[j][0] * inv;
    o.y = acc[j][1] * inv;
    o.z = acc[j][2] * inv;
    o.w = acc[j][3] * inv;
    *(float4*)(dst + (((size_t)(b * 81 + i * 9 + j) * 64 + h) << 7) + w0) = o;
  }
}

// ---------------------------------------------------------------------------
// Combine: out += channel-half-1 partial. 663,552 float4s, grid 2592 x 256.
// ---------------------------------------------------------------------------
__global__ __launch_bounds__(256) void combine_kernel(
    float* __restrict__ out, const float* __restrict__ part) {
  const size_t idx = (size_t)blockIdx.x * 256 + threadIdx.x;  // float4 index
  float4* o4       = (float4*)out;
  const float4* p4 = (const float4*)part;
  const float4 a = o4[idx], p = p4[idx];
  float4 rv;
  rv.x = a.x + p.x; rv.y = a.y + p.y; rv.z = a.z + p.z; rv.w = a.w + p.w;
  o4[idx] = rv;
}

// ---------------------------------------------------------------------------
extern "C" void kernel_launch(void* const* d_in, const int* in_sizes, int n_in,
                              void* d_out, int out_size, void* d_ws, size_t ws_size,
                              hipStream_t stream) {
  const float* feat1 = (const float*)d_in[0];
  const float* feat2 = (const float*)d_in[1];
  const float* w1    = (const float*)d_in[2];
  const float* b1    = (const float*)d_in[3];
  const float* w2    = (const float*)d_in[4];
  const float* b2    = (const float*)d_in[5];
  float* out = (float*)d_out;

  float* pooled = (float*)d_ws;                 // 82,944 floats
  float* At     = pooled + 82944;               // 82,944 floats
  float* cpart  = At + 82944;                   // 2,654,208 floats

  corr_pool_kernel<<<1024, 576, 0, stream>>>(feat1, feat2, pooled);
  mlp_kernel<<<4 * 81, 256, 0, stream>>>(pooled, w1, b1, w2, b2, At);
  out_kernel<<<2304, 64, 0, stream>>>(feat1, feat2, At, out, cpart);
  combine_kernel<<<2592, 256, 0, stream>>>(out, cpart);
}

// Round 10
// 198.930 us; speedup vs baseline: 1.0895x; 1.0035x over previous
//
#include <hip/hip_runtime.h>
#include <math.h>

// Problem constants (fixed): B=4, C=256, H=64, W=128, D=4, 81 shifts, C/R=16
// out: [B, 81, H, W] fp32 (2,654,208 elements)
// ws (floats): [0) pooled 82,944  [82944) At 82,944  [165888) cpart 2,654,208

#define HH 64
#define WW 128
#define CC 256
#define BB 4

// ---------------------------------------------------------------------------
// Kernel A: pooled[b, s, c] = sum_{h,w} f1[b,c,h,w] * f2pad[b,c,h+i,w+j]
// One 576-thread block (9 waves) per (b,c) plane; thread (h=t/9, di=t%9)
// owns a full row. REVERTED to the r0/r3 body: r9's f1-LDS staging pushed
// LDS to 73KB -> 2 blocks/CU (was 3) and cost ~7us net. Occupancy beats
// the saved global re-reads here.
// ---------------------------------------------------------------------------
__global__ __launch_bounds__(576) void corr_pool_kernel(
    const float* __restrict__ f1, const float* __restrict__ f2,
    float* __restrict__ pooled) {
  const int t  = threadIdx.x;
  const int bc = blockIdx.x;                    // b*256 + c
  const float* f1p = f1 + (size_t)bc * (HH * WW);
  const float* f2p = f2 + (size_t)bc * (HH * WW);

  __shared__ float4 f2s4[72 * 35];              // 40,320 B; reused for reduce

  // --- stage f2 plane with zero halo (single barrier) ---
  const float4 z4 = make_float4(0.f, 0.f, 0.f, 0.f);
  for (int u = t; u < 72 * 35; u += 576) {
    const int rl = u / 35, k = u - rl * 35;     // padded row, padded chunk
    const int gr = rl - 4;                      // f2 row
    float4 v = z4;
    if ((unsigned)gr < 64u && k >= 1 && k <= 32)
      v = *(const float4*)(f2p + (gr << 7) + ((k - 1) << 2));
    f2s4[u] = v;
  }
  __syncthreads();

  // --- stage 1: thread (h, di) accumulates s9[j] over its full row ---
  const int h  = t / 9;                         // 0..63
  const int di = t - h * 9;                     // 0..8
  const float4* f2row = &f2s4[(h + di) * 35];   // padded row h+di
  const float* f1row  = f1p + (h << 7);

  float s9[9];
#pragma unroll
  for (int j = 0; j < 9; ++j) s9[j] = 0.f;

  alignas(16) float f1c[16], f2wc[24];
#pragma unroll
  for (int m = 0; m < 4; ++m)
    *(float4*)&f1c[4 * m] = *(const float4*)(f1row + (m << 2));
#pragma unroll
  for (int m = 0; m < 6; ++m) *(float4*)&f2wc[4 * m] = f2row[m];

  for (int seg = 0; seg < 8; ++seg) {
    const int nxt = (seg < 7) ? seg + 1 : 7;    // clamped (dup load on last)
    alignas(16) float f1n[16], f2wn[24];
#pragma unroll
    for (int m = 0; m < 4; ++m)
      *(float4*)&f1n[4 * m] =
          *(const float4*)(f1row + (nxt << 4) + (m << 2));
#pragma unroll
    for (int m = 0; m < 6; ++m) *(float4*)&f2wn[4 * m] = f2row[(nxt << 2) + m];

#pragma unroll
    for (int k = 0; k < 16; ++k) {
      const float a = f1c[k];
#pragma unroll
      for (int j = 0; j < 9; ++j) s9[j] += a * f2wc[k + j];
    }
#pragma unroll
    for (int m = 0; m < 16; ++m) f1c[m] = f1n[m];
#pragma unroll
    for (int m = 0; m < 24; ++m) f2wc[m] = f2wn[m];
  }

  // --- stage 2: parallel column reduction (all 576 threads) ---
  __syncthreads();                              // stage-1 LDS reads done
  float* red  = (float*)f2s4;                   // [64][81]
  float* red2 = red + 64 * 81;                  // [7][81]
#pragma unroll
  for (int j = 0; j < 9; ++j) red[h * 81 + di * 9 + j] = s9[j];
  __syncthreads();

  if (t < 567) {                                // 7 groups x 81 cols
    const int col = t % 81, g = t / 81;
    const int r0 = g * 9, r1 = (g == 6) ? 64 : r0 + 9;
    float acc = 0.f;
#pragma unroll 3
    for (int rr = r0; rr < r1; ++rr) acc += red[rr * 81 + col];
    red2[g * 81 + col] = acc;
  }
  __syncthreads();

  if (t < 81) {
    float acc = 0.f;
#pragma unroll
    for (int g = 0; g < 7; ++g) acc += red2[g * 81 + t];
    const int b = bc >> 8, c = bc & 255;
    pooled[(size_t)(b * 81 + t) * 256 + c] = acc;   // raw sum (/8192 in B)
  }
}

// ---------------------------------------------------------------------------
// Kernel B: At[b, c, s] = sigmoid(MLP(pooled/8192)). Transposed output for
// kernel C's wave-uniform coefficient s_loads. UNCHANGED.
// ---------------------------------------------------------------------------
__global__ __launch_bounds__(256) void mlp_kernel(
    const float* __restrict__ pooled, const float* __restrict__ w1,
    const float* __restrict__ b1, const float* __restrict__ w2,
    const float* __restrict__ b2, float* __restrict__ At) {
  const int bs = blockIdx.x;                    // b*81 + s
  const int t  = threadIdx.x;
  const int b  = bs / 81;
  const int s  = bs - b * 81;
  __shared__ float p[256];
  __shared__ float hid[16];

  p[t] = pooled[(size_t)bs * 256 + t] * (1.0f / 8192.0f);
  __syncthreads();

  const int g = t >> 4, ln = t & 15;
  float acc = 0.f;
#pragma unroll
  for (int m = 0; m < 16; ++m) {
    const int c = (m << 4) + ln;
    acc += w1[(g << 8) + c] * p[c];
  }
  acc += __shfl_xor(acc, 1);
  acc += __shfl_xor(acc, 2);
  acc += __shfl_xor(acc, 4);
  acc += __shfl_xor(acc, 8);
  if (ln == 0) hid[g] = acc + b1[g];
  __syncthreads();

  float acc2 = b2[t];
#pragma unroll
  for (int k = 0; k < 16; ++k) acc2 += w2[(t << 4) + k] * hid[k];
  const float sv = 1.0f / (1.0f + __expf(-acc2));
  At[((size_t)(b * 256 + t)) * 81 + s] = sv;    // transposed: [b][c][81]
}

// ---------------------------------------------------------------------------
// One channel's window assembly + 9x4 FMA (macro keeps everything in the
// enclosing scope; mirrors the r0/r3 proven codegen pattern).
// ---------------------------------------------------------------------------
#define CH_BLOCK(x4, c4, cf)                                              \
  do {                                                                    \
    const float lx = __shfl_up(c4.x, 1), ly = __shfl_up(c4.y, 1);         \
    const float lz = __shfl_up(c4.z, 1), lw = __shfl_up(c4.w, 1);         \
    const float rx = __shfl_down(c4.x, 1), ry = __shfl_down(c4.y, 1);     \
    const float rz = __shfl_down(c4.z, 1), rw = __shfl_down(c4.w, 1);     \
    alignas(16) float f2r[12];                                            \
    f2r[0] = vA ? lx : 0.f;                                               \
    f2r[1] = vA ? ly : 0.f;                                               \
    f2r[2] = vA ? lz : 0.f;                                               \
    f2r[3] = vA ? lw : 0.f;                                               \
    f2r[4] = c4.x; f2r[5] = c4.y; f2r[6] = c4.z; f2r[7] = c4.w;           \
    f2r[8]  = vC ? rx : 0.f;                                              \
    f2r[9]  = vC ? ry : 0.f;                                              \
    f2r[10] = vC ? rz : 0.f;                                              \
    f2r[11] = vC ? rw : 0.f;                                              \
    alignas(16) const float xx[4] = {x4.x, x4.y, x4.z, x4.w};             \
    _Pragma("unroll")                                                     \
    for (int j = 0; j < 9; ++j) {                                         \
      const float wj = cf[j];                                             \
      _Pragma("unroll")                                                   \
      for (int k = 0; k < 4; ++k) acc[j][k] += wj * (xx[k] * f2r[k + j]); \
    }                                                                     \
  } while (0)

// ---------------------------------------------------------------------------
// Kernel C: channel-half partial of
//   out[b, i*9+j, h, w] = (1/256) sum_c At[b,c,i*9+j]*f1[c,h,w]*f2[c,h+i-4,w+j-4]
// Round-19: QUARTER-STRIDE CHANNEL BATCHING (32 trips x 4 channels).
// The decisive datum: r0 (8 loads/iter) == r3 (4 loads/iter) == 63us at 64
// iterations -- the ~2360cy/iter cost is INVARIANT to load count; it is a
// fixed per-TRIP serial cost (issue->wait->consume round trip + coef s_load
// chain). r1/r6/r8 varied traffic, never trip count. So: halve the trips.
// Each iteration processes channels c, c+32, c+64, c+96 of the 128-half
// (8 batched loads = r0's proven width, 4 coef s_load groups batched, ~680cy
// FMA). Shuffle windows retained from r3. Everything else identical.
// Success: dur <= 52us, VALUBusy 52-65%. Fail (flat ~63): fixed cost scales
// with channels, not trips -> structural plateau.
// ---------------------------------------------------------------------------
__global__ __launch_bounds__(64, 4) void out_kernel(
    const float* __restrict__ f1, const float* __restrict__ f2,
    const float* __restrict__ At, float* __restrict__ out,
    float* __restrict__ part) {
  // bid = x + 8*(i + 9*tq); tile = tq*8 + x keeps i-siblings on one XCD
  const int bid  = blockIdx.x;
  const int x    = bid & 7;
  const int q    = bid >> 3;                    // 0..287
  const int i    = q % 9;
  const int tq   = q / 9;                       // 0..31
  const int tile = tq * 8 + x;                  // 0..255
  const int half = tile & 1;
  const int rt   = (tile >> 1) & 31;
  const int b    = tile >> 6;
  const int h0   = rt << 1;

  const int t    = threadIdx.x;
  const int r    = t >> 5;                      // 0..1
  const int cidx = t & 31;
  const int w0   = cidx << 2;
  const int h    = h0 + r;
  const int hr   = h + i - 4;
  const bool rowok = ((unsigned)hr < 64u);

  float acc[9][4];
#pragma unroll
  for (int j = 0; j < 9; ++j)
#pragma unroll
    for (int k = 0; k < 4; ++k) acc[j][k] = 0.f;

  if (rowok) {
    const int c0 = half << 7;                   // 128-channel half base
    const float* p1a = f1 + (size_t)b * (CC * 8192) + (size_t)c0 * 8192 +
                       (h << 7) + w0;
    const float* p2a = f2 + (size_t)b * (CC * 8192) + (size_t)c0 * 8192 +
                       (hr << 7);
    const float* p1b = p1a + (size_t)32 * 8192;  // c+32
    const float* p2b = p2a + (size_t)32 * 8192;
    const float* p1c = p1a + (size_t)64 * 8192;  // c+64
    const float* p2c = p2a + (size_t)64 * 8192;
    const float* p1d = p1a + (size_t)96 * 8192;  // c+96
    const float* p2d = p2a + (size_t)96 * 8192;
    const float* Aa  = At + (size_t)b * (CC * 81) + (size_t)c0 * 81 + i * 9;

    const bool vA  = (cidx > 0);
    const bool vC  = (cidx < 31);

    for (int c = 0; c < 32; ++c) {
      // --- batch all 8 vector loads (four channels) ---
      const float4 xa = *(const float4*)(p1a);
      const float4 aB = *(const float4*)(p2a + w0);
      const float4 xb = *(const float4*)(p1b);
      const float4 bB = *(const float4*)(p2b + w0);
      const float4 xc = *(const float4*)(p1c);
      const float4 cB = *(const float4*)(p2c + w0);
      const float4 xd = *(const float4*)(p1d);
      const float4 dB = *(const float4*)(p2d + w0);

      const float* cfa = Aa + (size_t)c * 81;   // wave-uniform -> s_load
      const float* cfb = cfa + (size_t)32 * 81;
      const float* cfc = cfa + (size_t)64 * 81;
      const float* cfd = cfa + (size_t)96 * 81;

      const int adv = (c < 31) ? 8192 : 0;      // cndmask, no branch
      p1a += adv; p2a += adv; p1b += adv; p2b += adv;
      p1c += adv; p2c += adv; p1d += adv; p2d += adv;

      CH_BLOCK(xa, aB, cfa);
      CH_BLOCK(xb, bB, cfb);
      CH_BLOCK(xc, cB, cfc);
      CH_BLOCK(xd, dB, cfd);
    }
  }

  float* dst = half ? part : out;
  const float inv = 1.0f / 256.0f;
#pragma unroll
  for (int j = 0; j < 9; ++j) {
    float4 o;
    o.x = acc[j][0] * inv;
    o.y = acc[j][1] * inv;
    o.z = acc[j][2] * inv;
    o.w = acc[j][3] * inv;
    *(float4*)(dst + (((size_t)(b * 81 + i * 9 + j) * 64 + h) << 7) + w0) = o;
  }
}

// ---------------------------------------------------------------------------
// Combine: out += channel-half-1 partial. 663,552 float4s, grid 2592 x 256.
// ---------------------------------------------------------------------------
__global__ __launch_bounds__(256) void combine_kernel(
    float* __restrict__ out, const float* __restrict__ part) {
  const size_t idx = (size_t)blockIdx.x * 256 + threadIdx.x;  // float4 index
  float4* o4       = (float4*)out;
  const float4* p4 = (const float4*)part;
  const float4 a = o4[idx], p = p4[idx];
  float4 rv;
  rv.x = a.x + p.x; rv.y = a.y + p.y; rv.z = a.z + p.z; rv.w = a.w + p.w;
  o4[idx] = rv;
}

// ---------------------------------------------------------------------------
extern "C" void kernel_launch(void* const* d_in, const int* in_sizes, int n_in,
                              void* d_out, int out_size, void* d_ws, size_t ws_size,
                              hipStream_t stream) {
  const float* feat1 = (const float*)d_in[0];
  const float* feat2 = (const float*)d_in[1];
  const float* w1    = (const float*)d_in[2];
  const float* b1    = (const float*)d_in[3];
  const float* w2    = (const float*)d_in[4];
  const float* b2    = (const float*)d_in[5];
  float* out = (float*)d_out;

  float* pooled = (float*)d_ws;                 // 82,944 floats
  float* At     = pooled + 82944;               // 82,944 floats
  float* cpart  = At + 82944;                   // 2,654,208 floats

  corr_pool_kernel<<<1024, 576, 0, stream>>>(feat1, feat2, pooled);
  mlp_kernel<<<4 * 81, 256, 0, stream>>>(pooled, w1, b1, w2, b2, At);
  out_kernel<<<2304, 64, 0, stream>>>(feat1, feat2, At, out, cpart);
  combine_kernel<<<2592, 256, 0, stream>>>(out, cpart);
}

// Round 11
// 188.859 us; speedup vs baseline: 1.1476x; 1.0533x over previous
//
#include <hip/hip_runtime.h>
#include <math.h>

// Problem constants (fixed): B=4, C=256, H=64, W=128, D=4, 81 shifts, C/R=16
// out: [B, 81, H, W] fp32 (2,654,208 elements)
// ws (floats): [0) pooled 82,944  [82944) At 82,944  (cpart no longer used)

#define HH 64
#define WW 128
#define CC 256
#define BB 4

// ---------------------------------------------------------------------------
// Kernel A: pooled[b, s, c] = sum_{h,w} f1[b,c,h,w] * f2pad[b,c,h+i,w+j]
// One 576-thread block (9 waves) per (b,c) plane; thread (h=t/9, di=t%9)
// owns a full row. FROZEN at the r0 body (best measured; r9's LDS variant
// cost occupancy and regressed).
// ---------------------------------------------------------------------------
__global__ __launch_bounds__(576) void corr_pool_kernel(
    const float* __restrict__ f1, const float* __restrict__ f2,
    float* __restrict__ pooled) {
  const int t  = threadIdx.x;
  const int bc = blockIdx.x;                    // b*256 + c
  const float* f1p = f1 + (size_t)bc * (HH * WW);
  const float* f2p = f2 + (size_t)bc * (HH * WW);

  __shared__ float4 f2s4[72 * 35];              // 40,320 B; reused for reduce

  // --- stage f2 plane with zero halo (single barrier) ---
  const float4 z4 = make_float4(0.f, 0.f, 0.f, 0.f);
  for (int u = t; u < 72 * 35; u += 576) {
    const int rl = u / 35, k = u - rl * 35;     // padded row, padded chunk
    const int gr = rl - 4;                      // f2 row
    float4 v = z4;
    if ((unsigned)gr < 64u && k >= 1 && k <= 32)
      v = *(const float4*)(f2p + (gr << 7) + ((k - 1) << 2));
    f2s4[u] = v;
  }
  __syncthreads();

  // --- stage 1: thread (h, di) accumulates s9[j] over its full row ---
  const int h  = t / 9;                         // 0..63
  const int di = t - h * 9;                     // 0..8
  const float4* f2row = &f2s4[(h + di) * 35];   // padded row h+di
  const float* f1row  = f1p + (h << 7);

  float s9[9];
#pragma unroll
  for (int j = 0; j < 9; ++j) s9[j] = 0.f;

  alignas(16) float f1c[16], f2wc[24];
#pragma unroll
  for (int m = 0; m < 4; ++m)
    *(float4*)&f1c[4 * m] = *(const float4*)(f1row + (m << 2));
#pragma unroll
  for (int m = 0; m < 6; ++m) *(float4*)&f2wc[4 * m] = f2row[m];

  for (int seg = 0; seg < 8; ++seg) {
    const int nxt = (seg < 7) ? seg + 1 : 7;    // clamped (dup load on last)
    alignas(16) float f1n[16], f2wn[24];
#pragma unroll
    for (int m = 0; m < 4; ++m)
      *(float4*)&f1n[4 * m] =
          *(const float4*)(f1row + (nxt << 4) + (m << 2));
#pragma unroll
    for (int m = 0; m < 6; ++m) *(float4*)&f2wn[4 * m] = f2row[(nxt << 2) + m];

#pragma unroll
    for (int k = 0; k < 16; ++k) {
      const float a = f1c[k];
#pragma unroll
      for (int j = 0; j < 9; ++j) s9[j] += a * f2wc[k + j];
    }
#pragma unroll
    for (int m = 0; m < 16; ++m) f1c[m] = f1n[m];
#pragma unroll
    for (int m = 0; m < 24; ++m) f2wc[m] = f2wn[m];
  }

  // --- stage 2: parallel column reduction (all 576 threads) ---
  __syncthreads();                              // stage-1 LDS reads done
  float* red  = (float*)f2s4;                   // [64][81]
  float* red2 = red + 64 * 81;                  // [7][81]
#pragma unroll
  for (int j = 0; j < 9; ++j) red[h * 81 + di * 9 + j] = s9[j];
  __syncthreads();

  if (t < 567) {                                // 7 groups x 81 cols
    const int col = t % 81, g = t / 81;
    const int r0 = g * 9, r1 = (g == 6) ? 64 : r0 + 9;
    float acc = 0.f;
#pragma unroll 3
    for (int rr = r0; rr < r1; ++rr) acc += red[rr * 81 + col];
    red2[g * 81 + col] = acc;
  }
  __syncthreads();

  if (t < 81) {
    float acc = 0.f;
#pragma unroll
    for (int g = 0; g < 7; ++g) acc += red2[g * 81 + t];
    const int b = bc >> 8, c = bc & 255;
    pooled[(size_t)(b * 81 + t) * 256 + c] = acc;   // raw sum (/8192 in B)
  }
}

// ---------------------------------------------------------------------------
// Kernel B: At[b, c, s] = sigmoid(MLP(pooled/8192)). Transposed output for
// kernel C's wave-uniform coefficient s_loads. UNCHANGED.
// ---------------------------------------------------------------------------
__global__ __launch_bounds__(256) void mlp_kernel(
    const float* __restrict__ pooled, const float* __restrict__ w1,
    const float* __restrict__ b1, const float* __restrict__ w2,
    const float* __restrict__ b2, float* __restrict__ At) {
  const int bs = blockIdx.x;                    // b*81 + s
  const int t  = threadIdx.x;
  const int b  = bs / 81;
  const int s  = bs - b * 81;
  __shared__ float p[256];
  __shared__ float hid[16];

  p[t] = pooled[(size_t)bs * 256 + t] * (1.0f / 8192.0f);
  __syncthreads();

  const int g = t >> 4, ln = t & 15;
  float acc = 0.f;
#pragma unroll
  for (int m = 0; m < 16; ++m) {
    const int c = (m << 4) + ln;
    acc += w1[(g << 8) + c] * p[c];
  }
  acc += __shfl_xor(acc, 1);
  acc += __shfl_xor(acc, 2);
  acc += __shfl_xor(acc, 4);
  acc += __shfl_xor(acc, 8);
  if (ln == 0) hid[g] = acc + b1[g];
  __syncthreads();

  float acc2 = b2[t];
#pragma unroll
  for (int k = 0; k < 16; ++k) acc2 += w2[(t << 4) + k] * hid[k];
  const float sv = 1.0f / (1.0f + __expf(-acc2));
  At[((size_t)(b * 256 + t)) * 81 + s] = sv;    // transposed: [b][c][81]
}

// ---------------------------------------------------------------------------
// Kernel C: out[b, i*9+j, h, w] =
//   (1/256) sum_c At[b,c,i*9+j]*f1[c,h,w]*f2[c,h+i-4,w+j-4]
// Round-20: HALF-FUSION, BODY FROZEN. 10 rounds establish r3's per-wave
// loop as a local optimum (2360cy/pair at 9 waves/CU; every perturbation
// -- more waves r1, fewer loads r3, prefetch r2/r4/r7/r8, more streams
// r10 -- is neutral or worse; the limiter is a per-CU memory-path
// concurrency ceiling invisible to source-level control). This round takes
// the measured STRUCTURAL win instead: r1 showed non-out drops 129->117 us
// when combine_kernel is eliminated. Fuse the two channel-halves into one
// 128-thread block: wave 0 = half 0, wave 1 = half 1, each running the
// EXACT r3 loop (same 9 waves/CU, same 2 streams/wave, no in-loop
// barriers); one end-of-kernel LDS reduce ([9][64] float4 -> conflict-
// free) and wave 0 writes out directly. cpart + combine GONE; 3 launches.
// Predicted: out 63-66us, WRITE halves, total ~180.
// ---------------------------------------------------------------------------
__global__ __launch_bounds__(128, 4) void out_kernel(
    const float* __restrict__ f1, const float* __restrict__ f2,
    const float* __restrict__ At, float* __restrict__ out) {
  // bid = x + 8*(i + 9*tq); tile = tq*8 + x keeps i-siblings on one XCD
  const int bid  = blockIdx.x;                  // 0..1151
  const int x    = bid & 7;
  const int q    = bid >> 3;                    // 0..143
  const int i    = q % 9;
  const int tq   = q / 9;                       // 0..15
  const int tile = tq * 8 + x;                  // 0..127
  const int rt   = tile & 31;
  const int b    = tile >> 5;
  const int h0   = rt << 1;

  const int t    = threadIdx.x;
  const int wv   = t >> 6;                      // 0..1 = channel half
  const int lane = t & 63;
  const int r    = lane >> 5;                   // 0..1
  const int cidx = lane & 31;
  const int w0   = cidx << 2;
  const int h    = h0 + r;
  const int hr   = h + i - 4;
  const bool rowok = ((unsigned)hr < 64u);

  float acc[9][4];
#pragma unroll
  for (int j = 0; j < 9; ++j)
#pragma unroll
    for (int k = 0; k < 4; ++k) acc[j][k] = 0.f;

  if (rowok) {
    const int c0 = wv << 7;                     // 128-channel half base
    const float* pa1 = f1 + (size_t)b * (CC * 8192) + (size_t)c0 * 8192 +
                       (h << 7) + w0;
    const float* pa2 = f2 + (size_t)b * (CC * 8192) + (size_t)c0 * 8192 +
                       (hr << 7);
    const float* pb1 = pa1 + (size_t)64 * 8192; // paired channel c+64
    const float* pb2 = pa2 + (size_t)64 * 8192;
    const float* Aa  = At + (size_t)b * (CC * 81) + (size_t)c0 * 81 + i * 9;

    const bool vA  = (cidx > 0);
    const bool vC  = (cidx < 31);

    for (int c = 0; c < 64; ++c) {
      // --- 4 vector loads (two channels, center only) ---
      const float4 xa = *(const float4*)(pa1);
      const float4 aB = *(const float4*)(pa2 + w0);
      const float4 xb = *(const float4*)(pb1);
      const float4 bB = *(const float4*)(pb2 + w0);

      const float* ca = Aa + (size_t)c * 81;    // wave-uniform -> s_load
      const float* cb = ca + (size_t)64 * 81;

      const int adv = (c < 63) ? 8192 : 0;      // cndmask, no branch
      pa1 += adv; pa2 += adv; pb1 += adv; pb2 += adv;

      // --- neighbor window float4s from adjacent lanes (DS pipe) ---
      const float aAx = __shfl_up(aB.x, 1);
      const float aAy = __shfl_up(aB.y, 1);
      const float aAz = __shfl_up(aB.z, 1);
      const float aAw = __shfl_up(aB.w, 1);
      const float aCx = __shfl_down(aB.x, 1);
      const float aCy = __shfl_down(aB.y, 1);
      const float aCz = __shfl_down(aB.z, 1);
      const float aCw = __shfl_down(aB.w, 1);
      const float bAx = __shfl_up(bB.x, 1);
      const float bAy = __shfl_up(bB.y, 1);
      const float bAz = __shfl_up(bB.z, 1);
      const float bAw = __shfl_up(bB.w, 1);
      const float bCx = __shfl_down(bB.x, 1);
      const float bCy = __shfl_down(bB.y, 1);
      const float bCz = __shfl_down(bB.z, 1);
      const float bCw = __shfl_down(bB.w, 1);

      // --- channel a ---
      alignas(16) float f2ra[12];
      f2ra[0] = vA ? aAx : 0.f;
      f2ra[1] = vA ? aAy : 0.f;
      f2ra[2] = vA ? aAz : 0.f;
      f2ra[3] = vA ? aAw : 0.f;
      f2ra[4] = aB.x; f2ra[5] = aB.y; f2ra[6] = aB.z; f2ra[7] = aB.w;
      f2ra[8]  = vC ? aCx : 0.f;
      f2ra[9]  = vC ? aCy : 0.f;
      f2ra[10] = vC ? aCz : 0.f;
      f2ra[11] = vC ? aCw : 0.f;
      alignas(16) const float xxa[4] = {xa.x, xa.y, xa.z, xa.w};

#pragma unroll
      for (int j = 0; j < 9; ++j) {
        const float wj = ca[j];
#pragma unroll
        for (int k = 0; k < 4; ++k) acc[j][k] += wj * (xxa[k] * f2ra[k + j]);
      }

      // --- channel b (c+64) ---
      alignas(16) float f2rb[12];
      f2rb[0] = vA ? bAx : 0.f;
      f2rb[1] = vA ? bAy : 0.f;
      f2rb[2] = vA ? bAz : 0.f;
      f2rb[3] = vA ? bAw : 0.f;
      f2rb[4] = bB.x; f2rb[5] = bB.y; f2rb[6] = bB.z; f2rb[7] = bB.w;
      f2rb[8]  = vC ? bCx : 0.f;
      f2rb[9]  = vC ? bCy : 0.f;
      f2rb[10] = vC ? bCz : 0.f;
      f2rb[11] = vC ? bCw : 0.f;
      alignas(16) const float xxb[4] = {xb.x, xb.y, xb.z, xb.w};

#pragma unroll
      for (int j = 0; j < 9; ++j) {
        const float wj = cb[j];
#pragma unroll
        for (int k = 0; k < 4; ++k) acc[j][k] += wj * (xxb[k] * f2rb[k + j]);
      }
    }
  }

  // --- end-only cross-half reduction (one barrier, conflict-free) ---
  __shared__ float4 red[9][64];                 // 9,216 B
  if (wv == 1) {
#pragma unroll
    for (int j = 0; j < 9; ++j)
      red[j][lane] = make_float4(acc[j][0], acc[j][1], acc[j][2], acc[j][3]);
  }
  __syncthreads();

  if (wv == 0) {
    const float inv = 1.0f / 256.0f;
#pragma unroll
    for (int j = 0; j < 9; ++j) {
      const float4 p = red[j][lane];
      float4 o;
      o.x = (acc[j][0] + p.x) * inv;
      o.y = (acc[j][1] + p.y) * inv;
      o.z = (acc[j][2] + p.z) * inv;
      o.w = (acc[j][3] + p.w) * inv;
      *(float4*)(out + (((size_t)(b * 81 + i * 9 + j) * 64 + h) << 7) + w0) = o;
    }
  }
}

// ---------------------------------------------------------------------------
extern "C" void kernel_launch(void* const* d_in, const int* in_sizes, int n_in,
                              void* d_out, int out_size, void* d_ws, size_t ws_size,
                              hipStream_t stream) {
  const float* feat1 = (const float*)d_in[0];
  const float* feat2 = (const float*)d_in[1];
  const float* w1    = (const float*)d_in[2];
  const float* b1    = (const float*)d_in[3];
  const float* w2    = (const float*)d_in[4];
  const float* b2    = (const float*)d_in[5];
  float* out = (float*)d_out;

  float* pooled = (float*)d_ws;                 // 82,944 floats
  float* At     = pooled + 82944;               // 82,944 floats

  corr_pool_kernel<<<1024, 576, 0, stream>>>(feat1, feat2, pooled);
  mlp_kernel<<<4 * 81, 256, 0, stream>>>(pooled, w1, b1, w2, b2, At);
  out_kernel<<<1152, 128, 0, stream>>>(feat1, feat2, At, out);
}